// Round 2
// baseline (235.923 us; speedup 1.0000x reference)
//
#include <hip/hip_runtime.h>
#include <hip/hip_bf16.h>

typedef __attribute__((ext_vector_type(8))) short short8;
typedef __attribute__((ext_vector_type(4))) float f32x4;

#define B_  4
#define H_  16
#define T_  4096
#define D_  128
#define BS_ 32
#define C_  128
#define BH_ (B_ * H_)

// d-permutation making each MFMA fragment's 8 bf16 contiguous (16B):
// pos = chunk32*32 + q4*8 + half16*4 + low2   where d = chunk32*32 + half16*16 + q4*4 + low2
__device__ __forceinline__ int posperm(int x) {
  return (x & ~31) | (((x >> 2) & 3) << 3) | (((x >> 4) & 1) << 2) | (x & 3);
}

__device__ __forceinline__ unsigned short f2bf(float f) {
  __hip_bfloat16 h = __float2bfloat16(f);
  return __builtin_bit_cast(unsigned short, h);
}

// ---------------- compress: mean-pool k,v -> bf16 k_cmp [C][D], vT [D][C] ----------------
// Element at row r, position p stored at ushort index r*128 + (posperm(p) ^ ((r&7)<<3)).
__global__ __launch_bounds__(128) void compress_kernel(
    const float* __restrict__ k, const float* __restrict__ v,
    unsigned short* __restrict__ kc, unsigned short* __restrict__ vT) {
  int blk = blockIdx.x;
  int bh  = blk >> 7;
  int c   = blk & 127;
  int d   = threadIdx.x;
  const float* kp = k + ((size_t)bh * T_ + (size_t)c * BS_) * D_ + d;
  const float* vp = v + ((size_t)bh * T_ + (size_t)c * BS_) * D_ + d;
  float ksum = 0.f, vsum = 0.f;
#pragma unroll
  for (int j = 0; j < BS_; ++j) {
    ksum += kp[j * D_];
    vsum += vp[j * D_];
  }
  ksum *= (1.0f / BS_);
  vsum *= (1.0f / BS_);
  size_t slab = (size_t)bh * (C_ * D_);
  kc[slab + (size_t)c * D_ + (posperm(d) ^ ((c & 7) << 3))] = f2bf(ksum);
  vT[slab + (size_t)d * C_ + (posperm(c) ^ ((d & 7) << 3))] = f2bf(vsum);
}

// ---------------- attention over compressed KV ----------------
// Per WG: one head, 64 q-rows (4 waves x 16 rows). ONE 32 KB LDS buffer reused:
//   kc stage -> (QK^T) -> score bounce -> vT stage -> (PV as O^T) -> out bounce.
// Swapped QK^T: S^T[c][t], lane holds a full P-row slice; P feeds PV's B-operand
// directly; O^T acc has the same layout as S^T, so score and out share one
// coalesced store path (wave-private XOR-swizzled LDS transpose).
__global__ __launch_bounds__(256, 4) void attn_kernel(
    const float* __restrict__ q, const unsigned short* __restrict__ kc,
    const unsigned short* __restrict__ vT, float* __restrict__ out,
    float* __restrict__ score) {
  __shared__ uint4 sbuf[2048];  // 32 KB

  int blk    = blockIdx.x;
  int bh     = blk >> 6;
  int tchunk = blk & 63;
  int tid    = threadIdx.x;
  int wave   = tid >> 6;
  int lane   = tid & 63;
  int g      = lane >> 4;
  int lr     = lane & 15;
  int rx     = lr & 7;
  int t0     = tchunk * 64 + wave * 16;  // wave's 16 q-rows

  const uint4* kg = (const uint4*)(kc + (size_t)bh * (C_ * D_));
  const uint4* vg = (const uint4*)(vT + (size_t)bh * (C_ * D_));

  // stage kc -> LDS (block-linear)
  uint4 kreg[8];
#pragma unroll
  for (int it = 0; it < 8; ++it) kreg[it] = kg[it * 256 + tid];

  // preload vT into registers (wave-private mapping; consumed after score bounce)
  uint4 vreg[8];
  int vbase = wave * 512;
#pragma unroll
  for (int it = 0; it < 8; ++it) vreg[it] = vg[vbase + it * 64 + lane];

  // Q fragments (B operand): lane holds Q[t0+lr][d = 4g+(i&3)+16(i>>2)+32ks]
  const float scale = 0.08838834764831845f;  // 1/sqrt(128)
  short8 qf[4];
  const float* qrow = q + ((size_t)bh * T_ + t0 + lr) * D_;
#pragma unroll
  for (int ks = 0; ks < 4; ++ks) {
    int d0 = 4 * g + 32 * ks;
    float4 a = *(const float4*)(qrow + d0);
    float4 b = *(const float4*)(qrow + d0 + 16);
    short8 f;
    f[0] = (short)f2bf(a.x * scale); f[1] = (short)f2bf(a.y * scale);
    f[2] = (short)f2bf(a.z * scale); f[3] = (short)f2bf(a.w * scale);
    f[4] = (short)f2bf(b.x * scale); f[5] = (short)f2bf(b.y * scale);
    f[6] = (short)f2bf(b.z * scale); f[7] = (short)f2bf(b.w * scale);
    qf[ks] = f;
  }

#pragma unroll
  for (int it = 0; it < 8; ++it) sbuf[it * 256 + tid] = kreg[it];
  __syncthreads();

  // QK^T: accS[cm] = S^T[c = 4g+r+16cm][t = t0+lr]
  f32x4 accS[8];
#pragma unroll
  for (int cm = 0; cm < 8; ++cm) accS[cm] = f32x4{0.f, 0.f, 0.f, 0.f};
#pragma unroll
  for (int cm = 0; cm < 8; ++cm) {
    int rbase = (lr + 16 * cm) * 16;
#pragma unroll
    for (int ks = 0; ks < 4; ++ks) {
      uint4 kf = sbuf[rbase + ((4 * ks + g) ^ rx)];
      accS[cm] = __builtin_amdgcn_mfma_f32_16x16x32_bf16(
          __builtin_bit_cast(short8, kf), qf[ks], accS[cm], 0, 0, 0);
    }
  }

  // softmax over c (row t = t0+lr spread across lane-groups g)
  float m = -3.0e38f;
#pragma unroll
  for (int cm = 0; cm < 8; ++cm)
#pragma unroll
    for (int r = 0; r < 4; ++r) m = fmaxf(m, accS[cm][r]);
  m = fmaxf(m, __shfl_xor(m, 16));
  m = fmaxf(m, __shfl_xor(m, 32));

  float sum = 0.f;
#pragma unroll
  for (int cm = 0; cm < 8; ++cm) {
#pragma unroll
    for (int r = 0; r < 4; ++r) {
      float p = __expf(accS[cm][r] - m);
      accS[cm][r] = p;
      sum += p;
    }
  }
  sum += __shfl_xor(sum, 16);
  sum += __shfl_xor(sum, 32);
  float inv = 1.0f / sum;
#pragma unroll
  for (int cm = 0; cm < 8; ++cm)
#pragma unroll
    for (int r = 0; r < 4; ++r) accS[cm][r] *= inv;

  __syncthreads();  // all waves done reading kc from sbuf

  // ---- score bounce: wave-private 8 KB region, XOR-swizzled at 16B ----
  float* bw = (float*)sbuf + wave * 2048;
#pragma unroll
  for (int cm = 0; cm < 8; ++cm) {
    int c4 = (g + 4 * cm) ^ rx;
    *(f32x4*)&bw[lr * 128 + c4 * 4] = accS[cm];
  }
  float* dstS = score + ((size_t)bh * T_ + t0) * C_;
#pragma unroll
  for (int j = 0; j < 8; ++j) {
    int row = 2 * j + (lane >> 5);
    int c4  = lane & 31;
    f32x4 val = *(const f32x4*)&bw[row * 128 + (c4 ^ (row & 7)) * 4];
    *(f32x4*)&dstS[(size_t)row * C_ + c4 * 4] = val;
  }

  // pf: P^T fragments (k over c), from normalized accS
  short8 pf[4];
#pragma unroll
  for (int ks = 0; ks < 4; ++ks) {
    short8 f;
#pragma unroll
    for (int r = 0; r < 4; ++r) {
      f[r]     = (short)f2bf(accS[2 * ks][r]);
      f[4 + r] = (short)f2bf(accS[2 * ks + 1][r]);
    }
    pf[ks] = f;
  }

  // stage vT into own region (bounce reads above already consumed)
#pragma unroll
  for (int it = 0; it < 8; ++it) sbuf[vbase + it * 64 + lane] = vreg[it];
  __syncthreads();

  // PV as O^T: o[nt] holds O^T[d = 4g+r+16nt][t = t0+lr]
  f32x4 o[8];
#pragma unroll
  for (int nt = 0; nt < 8; ++nt) o[nt] = f32x4{0.f, 0.f, 0.f, 0.f};
#pragma unroll
  for (int nt = 0; nt < 8; ++nt) {
    int rbase = (lr + 16 * nt) * 16;
#pragma unroll
    for (int ks = 0; ks < 4; ++ks) {
      uint4 vf = sbuf[rbase + ((4 * ks + g) ^ rx)];
      o[nt] = __builtin_amdgcn_mfma_f32_16x16x32_bf16(
          __builtin_bit_cast(short8, vf), pf[ks], o[nt], 0, 0, 0);
    }
  }
  __syncthreads();  // all waves done reading vT

  // ---- out bounce: same path as score ----
#pragma unroll
  for (int nt = 0; nt < 8; ++nt) {
    int c4 = (g + 4 * nt) ^ rx;
    *(f32x4*)&bw[lr * 128 + c4 * 4] = o[nt];
  }
  float* dstO = out + ((size_t)bh * T_ + t0) * D_;
#pragma unroll
  for (int j = 0; j < 8; ++j) {
    int row = 2 * j + (lane >> 5);
    int c4  = lane & 31;
    f32x4 val = *(const f32x4*)&bw[row * 128 + (c4 ^ (row & 7)) * 4];
    *(f32x4*)&dstO[(size_t)row * D_ + c4 * 4] = val;
  }
}

extern "C" void kernel_launch(void* const* d_in, const int* in_sizes, int n_in,
                              void* d_out, int out_size, void* d_ws, size_t ws_size,
                              hipStream_t stream) {
  const float* q = (const float*)d_in[0];
  const float* k = (const float*)d_in[1];
  const float* v = (const float*)d_in[2];
  float* out   = (float*)d_out;
  float* score = out + (size_t)BH_ * T_ * D_;

  unsigned short* kc = (unsigned short*)d_ws;       // 2 MB
  unsigned short* vT = kc + (size_t)BH_ * C_ * D_;  // 2 MB

  compress_kernel<<<BH_ * C_, 128, 0, stream>>>(k, v, kc, vT);
  attn_kernel<<<BH_ * 64, 256, 0, stream>>>(q, kc, vT, out, score);
}

// Round 3
// 147.975 us; speedup vs baseline: 1.5943x; 1.5943x over previous
//
#include <hip/hip_runtime.h>
#include <hip/hip_bf16.h>

typedef __attribute__((ext_vector_type(8))) short short8;
typedef __attribute__((ext_vector_type(4))) float f32x4;

#define B_  4
#define H_  16
#define T_  4096
#define D_  128
#define BS_ 32
#define C_  128
#define BH_ (B_ * H_)

// d-permutation making each MFMA fragment's 8 bf16 contiguous (16B):
// pos = chunk32*32 + q4*8 + half16*4 + low2   where d = chunk32*32 + half16*16 + q4*4 + low2
// Aligned quads are preserved: posperm(4l+i) = posperm(4l) + i, i in 0..3.
__device__ __forceinline__ int posperm(int x) {
  return (x & ~31) | (((x >> 2) & 3) << 3) | (((x >> 4) & 1) << 2) | (x & 3);
}

__device__ __forceinline__ unsigned short f2bf(float f) {
  __hip_bfloat16 h = __float2bfloat16(f);
  return __builtin_bit_cast(unsigned short, h);
}

// ---------------- compress: mean-pool k,v -> bf16 k_cmp [C][D], vT [D][C] ----------------
// Element at row r, position p stored at ushort index r*128 + (posperm(p) ^ ((r&7)<<3)).
// 256 threads = 8 c-blocks per WG; each thread owns one d-quad of one c-block
// (float4 loads, 16B/lane; 32 lanes of a c-block read contiguous 512B rows).
__global__ __launch_bounds__(256) void compress_kernel(
    const float* __restrict__ k, const float* __restrict__ v,
    unsigned short* __restrict__ kc, unsigned short* __restrict__ vT) {
  int blk = blockIdx.x;
  int bh  = blk >> 4;
  int cg  = blk & 15;
  int cb  = cg * 8 + (threadIdx.x >> 5);  // c-block index 0..127
  int l   = threadIdx.x & 31;             // d-quad index
  const float* kp = k + ((size_t)bh * T_ + (size_t)cb * BS_) * D_ + 4 * l;
  const float* vp = v + ((size_t)bh * T_ + (size_t)cb * BS_) * D_ + 4 * l;
  float4 ks = {0.f, 0.f, 0.f, 0.f}, vs = {0.f, 0.f, 0.f, 0.f};
#pragma unroll
  for (int j = 0; j < BS_; ++j) {
    float4 a = *(const float4*)(kp + (size_t)j * D_);
    float4 b = *(const float4*)(vp + (size_t)j * D_);
    ks.x += a.x; ks.y += a.y; ks.z += a.z; ks.w += a.w;
    vs.x += b.x; vs.y += b.y; vs.z += b.z; vs.w += b.w;
  }
  const float s = 1.0f / BS_;
  size_t slab = (size_t)bh * (C_ * D_);
  // kc: one 8B store of 4 contiguous (post-perm) ushorts
  unsigned short kq[4] = {f2bf(ks.x * s), f2bf(ks.y * s), f2bf(ks.z * s), f2bf(ks.w * s)};
  int p0 = posperm(4 * l) ^ ((cb & 7) << 3);
  *(uint2*)&kc[slab + (size_t)cb * D_ + p0] =
      *(const uint2*)kq;
  // vT: 4 scalar stores (d varies -> different rows)
  float vv[4] = {vs.x * s, vs.y * s, vs.z * s, vs.w * s};
#pragma unroll
  for (int i = 0; i < 4; ++i) {
    int d = 4 * l + i;
    vT[slab + (size_t)d * C_ + (posperm(cb) ^ ((d & 7) << 3))] = f2bf(vv[i]);
  }
}

// ---------------- attention over compressed KV ----------------
// Per WG: one head, 64 q-rows (4 waves x 16 rows). LDS 64KB: kc 32KB + vT 32KB.
// After QK^T the kc region is dead -> reused as wave-private bounce buffer so
// BOTH outputs store as fully coalesced 16B/lane streams.
// Swapped QK^T: accS[cm] = S^T[c=4g+r+16cm][t0+lr]  (f32x4 over r = 4 contiguous
// c of score row t0+lr).  PV as O^T: o = mfma(vf, pf) -> same acc shape for out.
__global__ __launch_bounds__(256, 2) void attn_kernel(
    const float* __restrict__ q, const unsigned short* __restrict__ kc,
    const unsigned short* __restrict__ vT, float* __restrict__ out,
    float* __restrict__ score) {
  __shared__ uint4 sbuf[4096];  // [0..2047]=kc (later bounce), [2048..4095]=vT

  int blk    = blockIdx.x;
  int bh     = blk >> 6;
  int tchunk = blk & 63;
  int tid    = threadIdx.x;
  int wave   = tid >> 6;
  int lane   = tid & 63;
  int g      = lane >> 4;
  int lr     = lane & 15;
  int rx     = lr & 7;
  int t0     = tchunk * 64 + wave * 16;  // wave's 16 q-rows

  const uint4* kg = (const uint4*)(kc + (size_t)bh * (C_ * D_));
  const uint4* vg = (const uint4*)(vT + (size_t)bh * (C_ * D_));
#pragma unroll
  for (int it = 0; it < 8; ++it) {
    sbuf[it * 256 + tid]        = kg[it * 256 + tid];
    sbuf[2048 + it * 256 + tid] = vg[it * 256 + tid];
  }

  // Q fragments (B operand): lane holds Q[t0+lr][d = 4g+(i&3)+16(i>>2)+32ks]
  const float scale = 0.08838834764831845f;  // 1/sqrt(128)
  short8 qf[4];
  const float* qrow = q + ((size_t)bh * T_ + t0 + lr) * D_;
#pragma unroll
  for (int ks = 0; ks < 4; ++ks) {
    int d0 = 4 * g + 32 * ks;
    float4 a = *(const float4*)(qrow + d0);
    float4 b = *(const float4*)(qrow + d0 + 16);
    short8 f;
    f[0] = (short)f2bf(a.x * scale); f[1] = (short)f2bf(a.y * scale);
    f[2] = (short)f2bf(a.z * scale); f[3] = (short)f2bf(a.w * scale);
    f[4] = (short)f2bf(b.x * scale); f[5] = (short)f2bf(b.y * scale);
    f[6] = (short)f2bf(b.z * scale); f[7] = (short)f2bf(b.w * scale);
    qf[ks] = f;
  }
  __syncthreads();

  // QK^T: accS[cm] = S^T[c = 4g+r+16cm][t = t0+lr]
  f32x4 accS[8];
#pragma unroll
  for (int cm = 0; cm < 8; ++cm) accS[cm] = f32x4{0.f, 0.f, 0.f, 0.f};
#pragma unroll
  for (int cm = 0; cm < 8; ++cm) {
    int rbase = (lr + 16 * cm) * 16;
#pragma unroll
    for (int ks = 0; ks < 4; ++ks) {
      uint4 kf = sbuf[rbase + ((4 * ks + g) ^ rx)];
      accS[cm] = __builtin_amdgcn_mfma_f32_16x16x32_bf16(
          __builtin_bit_cast(short8, kf), qf[ks], accS[cm], 0, 0, 0);
    }
  }

  // softmax over c (row t = t0+lr spread across lane-groups g)
  float m = -3.0e38f;
#pragma unroll
  for (int cm = 0; cm < 8; ++cm)
#pragma unroll
    for (int r = 0; r < 4; ++r) m = fmaxf(m, accS[cm][r]);
  m = fmaxf(m, __shfl_xor(m, 16));
  m = fmaxf(m, __shfl_xor(m, 32));

  float sum = 0.f;
#pragma unroll
  for (int cm = 0; cm < 8; ++cm) {
#pragma unroll
    for (int r = 0; r < 4; ++r) {
      float p = __expf(accS[cm][r] - m);
      accS[cm][r] = p;
      sum += p;
    }
  }
  sum += __shfl_xor(sum, 16);
  sum += __shfl_xor(sum, 32);
  float inv = 1.0f / sum;
#pragma unroll
  for (int cm = 0; cm < 8; ++cm)
#pragma unroll
    for (int r = 0; r < 4; ++r) accS[cm][r] *= inv;

  __syncthreads();  // all waves done reading kc region

  // ---- score bounce through dead kc region (wave-private 8 KB) ----
  float* bw = (float*)sbuf + wave * 2048;
#pragma unroll
  for (int cm = 0; cm < 8; ++cm) {
    int c4 = (g + 4 * cm) ^ rx;
    *(f32x4*)&bw[lr * 128 + c4 * 4] = accS[cm];
  }
  float* dstS = score + ((size_t)bh * T_ + t0) * C_;
#pragma unroll
  for (int j = 0; j < 8; ++j) {
    int row = 2 * j + (lane >> 5);
    int c4  = lane & 31;
    f32x4 val = *(const f32x4*)&bw[row * 128 + (c4 ^ (row & 7)) * 4];
    *(f32x4*)&dstS[(size_t)row * C_ + c4 * 4] = val;
  }

  // pf: P^T fragments (k over c), from normalized accS
  short8 pf[4];
#pragma unroll
  for (int ks = 0; ks < 4; ++ks) {
    short8 f;
#pragma unroll
    for (int r = 0; r < 4; ++r) {
      f[r]     = (short)f2bf(accS[2 * ks][r]);
      f[4 + r] = (short)f2bf(accS[2 * ks + 1][r]);
    }
    pf[ks] = f;
  }

  // PV as O^T: o = O^T[d = 4g+r+16nt][t0+lr]; bounce-write immediately (o reused)
  const uint4* vbuf = sbuf + 2048;
#pragma unroll
  for (int nt = 0; nt < 8; ++nt) {
    f32x4 o = f32x4{0.f, 0.f, 0.f, 0.f};
    int rbase = (lr + 16 * nt) * 16;
#pragma unroll
    for (int ks = 0; ks < 4; ++ks) {
      uint4 vf = vbuf[rbase + ((4 * ks + g) ^ rx)];
      o = __builtin_amdgcn_mfma_f32_16x16x32_bf16(
          __builtin_bit_cast(short8, vf), pf[ks], o, 0, 0, 0);
    }
    int c4 = (g + 4 * nt) ^ rx;
    *(f32x4*)&bw[lr * 128 + c4 * 4] = o;
  }
  // ---- out bounce read + coalesced stores ----
  float* dstO = out + ((size_t)bh * T_ + t0) * D_;
#pragma unroll
  for (int j = 0; j < 8; ++j) {
    int row = 2 * j + (lane >> 5);
    int c4  = lane & 31;
    f32x4 val = *(const f32x4*)&bw[row * 128 + (c4 ^ (row & 7)) * 4];
    *(f32x4*)&dstO[(size_t)row * D_ + c4 * 4] = val;
  }
}

extern "C" void kernel_launch(void* const* d_in, const int* in_sizes, int n_in,
                              void* d_out, int out_size, void* d_ws, size_t ws_size,
                              hipStream_t stream) {
  const float* q = (const float*)d_in[0];
  const float* k = (const float*)d_in[1];
  const float* v = (const float*)d_in[2];
  float* out   = (float*)d_out;
  float* score = out + (size_t)BH_ * T_ * D_;

  unsigned short* kc = (unsigned short*)d_ws;       // 2 MB
  unsigned short* vT = kc + (size_t)BH_ * C_ * D_;  // 2 MB

  compress_kernel<<<BH_ * 16, 256, 0, stream>>>(k, v, kc, vT);
  attn_kernel<<<BH_ * 64, 256, 0, stream>>>(q, kc, vT, out, score);
}